// Round 1
// baseline (1038.667 us; speedup 1.0000x reference)
//
#include <hip/hip_runtime.h>
#include <hip/hip_bf16.h>

// Problem constants (from reference)
#define E_   8
#define D_   1024
#define H_   4096
#define T_   8192      // B*S tokens
#define TMM  128       // GEMM M tile (tokens)
#define TNN  256       // GEMM N tile
#define BK   64        // GEMM K chunk (bf16)
#define CAP  17408     // 136*128 >= 16384 + 8*127 padded capacity
#define NBY  136       // CAP/TMM
#define CK   2         // fc2 K-split (K=4096 -> 2 x 2048), separate y slices

typedef __attribute__((ext_vector_type(8))) short short8;   // 8 bf16 (MFMA A/B frag, 4 VGPR)
typedef __attribute__((ext_vector_type(4))) float floatx4;  // 16x16 MFMA C/D frag

__device__ __forceinline__ unsigned short f2bf(float f) {
    unsigned u = __float_as_uint(f);
    u += 0x7fffu + ((u >> 16) & 1u);   // RNE truncate to bf16
    return (unsigned short)(u >> 16);
}
__device__ __forceinline__ float bf2f(unsigned short u) {
    return __uint_as_float((unsigned)u << 16);
}

// direct global->LDS async copy, 16B/lane; lds base must be wave-uniform
#define GLP16(g, l)                                                             \
    __builtin_amdgcn_global_load_lds((const __attribute__((address_space(1))) void*)(g), \
                                     (__attribute__((address_space(3))) void*)(l), 16, 0, 0)

// ---------------- Router: 4 waves/block, 1 token/wave, float4 loads ----------------
__global__ __launch_bounds__(256) void router_kernel(
    const float* __restrict__ x, const float* __restrict__ Wr,
    int* __restrict__ cnt, int* __restrict__ tok_list,
    int2* __restrict__ inv_ei, float2* __restrict__ inv_w)
{
    int t = blockIdx.x * 4 + (threadIdx.x >> 6);
    int lane = threadIdx.x & 63;
    const float4* xr = (const float4*)(x + (size_t)t * D_);
    float acc[E_];
#pragma unroll
    for (int e = 0; e < E_; ++e) acc[e] = 0.f;
#pragma unroll
    for (int it = 0; it < D_ / 256; ++it) {
        float4 xv = xr[lane + it * 64];
#pragma unroll
        for (int e = 0; e < E_; ++e) {
            float4 wv = ((const float4*)(Wr + e * D_))[lane + it * 64];
            acc[e] += xv.x * wv.x + xv.y * wv.y + xv.z * wv.z + xv.w * wv.w;
        }
    }
#pragma unroll
    for (int e = 0; e < E_; ++e) {
#pragma unroll
        for (int off = 32; off; off >>= 1) acc[e] += __shfl_xor(acc[e], off);
    }
    if (lane == 0) {
        float m = acc[0];
#pragma unroll
        for (int e = 1; e < E_; ++e) m = fmaxf(m, acc[e]);
        float p[E_]; float s = 0.f;
#pragma unroll
        for (int e = 0; e < E_; ++e) { p[e] = expf(acc[e] - m); s += p[e]; }
        float inv = 1.f / s;
        int i1 = 0; float v1 = p[0];
#pragma unroll
        for (int e = 1; e < E_; ++e) if (p[e] > v1) { v1 = p[e]; i1 = e; }
        int i2 = -1; float v2 = -1.f;
#pragma unroll
        for (int e = 0; e < E_; ++e) { if (e == i1) continue; if (p[e] > v2) { v2 = p[e]; i2 = e; } }
        v1 *= inv; v2 *= inv;
        int pos1 = atomicAdd(&cnt[i1], 1);
        tok_list[i1 * T_ + pos1] = t;
        int pos2 = atomicAdd(&cnt[i2], 1);
        tok_list[i2 * T_ + pos2] = t;
        inv_ei[t] = make_int2(i1 | (pos1 << 3), i2 | (pos2 << 3));
        inv_w[t] = make_float2(v1, v2);
    }
}

// ---------------- Prefix: 128-aligned expert regions ----------------
__global__ void offsets_kernel(const int* __restrict__ cnt, int* __restrict__ start)
{
    if (threadIdx.x == 0) {
        int s = 0;
        for (int e = 0; e < E_; ++e) {
            start[e] = s;
            s += (cnt[e] + TMM - 1) / TMM * TMM;
        }
        start[E_] = s;
    }
}

// ---------------- Gather x rows -> bf16 ----------------
__global__ __launch_bounds__(256) void gather_kernel(
    const float* __restrict__ x, const int* __restrict__ cnt, const int* __restrict__ start,
    const int* __restrict__ tok_list, unsigned short* __restrict__ xg)
{
    int row = blockIdx.x;
    int tid = threadIdx.x;
    int tot = start[E_];
    if (row >= tot) return;
    int e = 0;
    while (e < E_ - 1 && row >= start[e + 1]) ++e;
    int idx = row - start[e];
    unsigned short* dst = xg + (size_t)row * D_;
    if (idx < cnt[e]) {
        int t = tok_list[e * T_ + idx];
        const float4* src = (const float4*)(x + (size_t)t * D_);
        float4 v = src[tid];
        ushort4 o; o.x = f2bf(v.x); o.y = f2bf(v.y); o.z = f2bf(v.z); o.w = f2bf(v.w);
        ((ushort4*)dst)[tid] = o;
    } else {
        ((ushort4*)dst)[tid] = make_ushort4(0, 0, 0, 0);  // zero pad rows
    }
}

// ---------------- fc1: h = gelu(Xg @ W1 + b1), bf16 out ----------------
// 128x256 tile, 512 threads (8 waves, 2m x 4n), each wave 4x4 frags of 16x16x32.
// A: global_load_lds from gathered bf16 xg (unchanged, verified path).
// B: fused transpose+cvt staging straight from the ORIGINAL f32 W1 [D][H]:
//    each thread loads a 4k x 4n f32 micro-tile (coalesced), converts to bf16 in
//    regs, and ds_write_b64's it into the same XOR-swizzled Bsm layout the
//    readers already use. Lane->k-group map gsl=(wid+(lane>>4))&7 plus k-parity
//    (lane>>3)&1 spreads each write instruction over all 32 banks (conflict-free).
__global__ __launch_bounds__(512, 4) void fc1_kernel(
    const unsigned short* __restrict__ xg, const float* __restrict__ W1,
    const float* __restrict__ b1, const int* __restrict__ start, unsigned short* __restrict__ h)
{
    __shared__ __align__(16) unsigned short Asm[TMM * BK];   // 16 KB
    __shared__ __align__(16) unsigned short Bsm[TNN * BK];   // 32 KB

    int row0 = blockIdx.y * TMM;
    int tot = start[E_];
    if (row0 >= tot) return;
    int e = 0;
    while (e < E_ - 1 && row0 >= start[e + 1]) ++e;

    int n0 = blockIdx.x * TNN;
    const unsigned short* Ag = xg + (size_t)row0 * D_;
    const float* Bg = W1 + (size_t)e * D_ * H_ + n0;   // f32 [K=D_][N=H_] panel

    int tid = threadIdx.x;
    int wid = tid >> 6, lane = tid & 63;
    int wm = wid & 1, wn = wid >> 1;          // wave covers rows wm*64+, cols wn*64+
    int quad = lane >> 4, r16 = lane & 15;
    int srow = lane >> 3;                      // 0..7
    int scol = ((lane & 7) ^ srow) * 8;        // swizzled 16B group (A path)
    int rsw = r16 & 7;                         // reader XOR key
    int gsl = (wid + (lane >> 4)) & 7;         // B: k-group (8 elems) this lane stages
    int kparl = (lane >> 3) & 1;               // B: k4-parity selector

    floatx4 acc[4][4];
#pragma unroll
    for (int i = 0; i < 4; ++i)
#pragma unroll
        for (int j = 0; j < 4; ++j) acc[i][j] = (floatx4){0.f, 0.f, 0.f, 0.f};

    for (int kc = 0; kc < D_ / BK; ++kc) {
        int k0 = kc * BK;
#pragma unroll
        for (int q = 0; q < 2; ++q) {
            int rb = wid * 16 + q * 8;
            GLP16(Ag + (size_t)(rb + srow) * D_ + k0 + scol, Asm + rb * BK);
        }
        // B staging: 2 micro-tiles of 4k x 4n per thread
#pragma unroll
        for (int m = 0; m < 2; ++m) {
            int k4 = gsl * 2 + (kparl ^ m);           // 0..15, per-lane
            const float* src = Bg + (size_t)(k0 + k4 * 4) * H_ + 4 * lane;
            float4 r0 = *(const float4*)(src);
            float4 r1 = *(const float4*)(src + H_);
            float4 r2 = *(const float4*)(src + 2 * H_);
            float4 r3 = *(const float4*)(src + 3 * H_);
            int h2 = (k4 & 1) * 4;                     // half-slot offset (k&7 in {0,4})
#define BW_(J, c) { int nrow = 4 * lane + J;                                         \
        ushort4 o; o.x = f2bf(r0.c); o.y = f2bf(r1.c); o.z = f2bf(r2.c); o.w = f2bf(r3.c); \
        *(ushort4*)(Bsm + nrow * BK + ((gsl ^ (nrow & 7)) << 3) + h2) = o; }
            BW_(0, x) BW_(1, y) BW_(2, z) BW_(3, w)
#undef BW_
        }
        __syncthreads();
#pragma unroll
        for (int ks = 0; ks < 2; ++ks) {
            short8 af[4], bfr[4];
#pragma unroll
            for (int i = 0; i < 4; ++i)
                af[i] = *(const short8*)(Asm + (wm * 64 + i * 16 + r16) * BK + ((ks * 4 + quad) ^ rsw) * 8);
#pragma unroll
            for (int j = 0; j < 4; ++j)
                bfr[j] = *(const short8*)(Bsm + (wn * 64 + j * 16 + r16) * BK + ((ks * 4 + quad) ^ rsw) * 8);
#pragma unroll
            for (int i = 0; i < 4; ++i)
#pragma unroll
                for (int j = 0; j < 4; ++j)
                    acc[i][j] = __builtin_amdgcn_mfma_f32_16x16x32_bf16(af[i], bfr[j], acc[i][j], 0, 0, 0);
        }
        __syncthreads();
    }

    const float* b1e = b1 + (size_t)e * H_;
    float bj[4];
#pragma unroll
    for (int j = 0; j < 4; ++j) bj[j] = b1e[n0 + wn * 64 + j * 16 + r16];
#pragma unroll
    for (int i = 0; i < 4; ++i) {
#pragma unroll
        for (int r = 0; r < 4; ++r) {
            size_t rowg = (size_t)row0 + wm * 64 + i * 16 + quad * 4 + r;
            unsigned short* hp = h + rowg * H_ + n0 + wn * 64 + r16;
#pragma unroll
            for (int j = 0; j < 4; ++j) {
                float v = acc[i][j][r] + bj[j];
                // tanh-form gelu: v * sigmoid(1.5957691*(v + 0.044715 v^3)); max err ~3e-4
                float u = 1.5957691f * v * fmaf(0.044715f, v * v, 1.f);
                float gl = v * __builtin_amdgcn_rcpf(1.f + __expf(-u));
                hp[j * 16] = f2bf(gl);
            }
        }
    }
}

// ---------------- fc2: y_s = h @ W2 (K-slice s), bf16 out, NO atomics ----------------
// Same fused B-staging, from f32 W2 [K=H_][N=D_]. A: global_load_lds from h.
__global__ __launch_bounds__(512, 4) void fc2_kernel(
    const unsigned short* __restrict__ h, const float* __restrict__ W2,
    const int* __restrict__ start, unsigned short* __restrict__ y)
{
    __shared__ __align__(16) unsigned short Asm[TMM * BK];
    __shared__ __align__(16) unsigned short Bsm[TNN * BK];

    int row0 = blockIdx.y * TMM;
    int tot = start[E_];
    if (row0 >= tot) return;
    int e = 0;
    while (e < E_ - 1 && row0 >= start[e + 1]) ++e;

    int nblk = blockIdx.x & 3, ck = blockIdx.x >> 2;
    int n0 = nblk * TNN;
    const unsigned short* Ag = h + (size_t)row0 * H_;
    const float* Bg = W2 + (size_t)e * H_ * D_ + n0;   // f32 [K=H_][N=D_] panel

    int tid = threadIdx.x;
    int wid = tid >> 6, lane = tid & 63;
    int wm = wid & 1, wn = wid >> 1;
    int quad = lane >> 4, r16 = lane & 15;
    int srow = lane >> 3;
    int scol = ((lane & 7) ^ srow) * 8;
    int rsw = r16 & 7;
    int gsl = (wid + (lane >> 4)) & 7;
    int kparl = (lane >> 3) & 1;

    floatx4 acc[4][4];
#pragma unroll
    for (int i = 0; i < 4; ++i)
#pragma unroll
        for (int j = 0; j < 4; ++j) acc[i][j] = (floatx4){0.f, 0.f, 0.f, 0.f};

    const int KITERS = H_ / BK / CK;           // 32
    int kbase = ck * KITERS;
    for (int kc = kbase; kc < kbase + KITERS; ++kc) {
        int k0 = kc * BK;
#pragma unroll
        for (int q = 0; q < 2; ++q) {
            int rb = wid * 16 + q * 8;
            GLP16(Ag + (size_t)(rb + srow) * H_ + k0 + scol, Asm + rb * BK);
        }
#pragma unroll
        for (int m = 0; m < 2; ++m) {
            int k4 = gsl * 2 + (kparl ^ m);
            const float* src = Bg + (size_t)(k0 + k4 * 4) * D_ + 4 * lane;
            float4 r0 = *(const float4*)(src);
            float4 r1 = *(const float4*)(src + D_);
            float4 r2 = *(const float4*)(src + 2 * D_);
            float4 r3 = *(const float4*)(src + 3 * D_);
            int h2 = (k4 & 1) * 4;
#define BW_(J, c) { int nrow = 4 * lane + J;                                         \
        ushort4 o; o.x = f2bf(r0.c); o.y = f2bf(r1.c); o.z = f2bf(r2.c); o.w = f2bf(r3.c); \
        *(ushort4*)(Bsm + nrow * BK + ((gsl ^ (nrow & 7)) << 3) + h2) = o; }
            BW_(0, x) BW_(1, y) BW_(2, z) BW_(3, w)
#undef BW_
        }
        __syncthreads();
#pragma unroll
        for (int ks = 0; ks < 2; ++ks) {
            short8 af[4], bfr[4];
#pragma unroll
            for (int i = 0; i < 4; ++i)
                af[i] = *(const short8*)(Asm + (wm * 64 + i * 16 + r16) * BK + ((ks * 4 + quad) ^ rsw) * 8);
#pragma unroll
            for (int j = 0; j < 4; ++j)
                bfr[j] = *(const short8*)(Bsm + (wn * 64 + j * 16 + r16) * BK + ((ks * 4 + quad) ^ rsw) * 8);
#pragma unroll
            for (int i = 0; i < 4; ++i)
#pragma unroll
                for (int j = 0; j < 4; ++j)
                    acc[i][j] = __builtin_amdgcn_mfma_f32_16x16x32_bf16(af[i], bfr[j], acc[i][j], 0, 0, 0);
        }
        __syncthreads();
    }

    unsigned short* ys = y + (size_t)ck * CAP * D_;
#pragma unroll
    for (int i = 0; i < 4; ++i) {
#pragma unroll
        for (int r = 0; r < 4; ++r) {
            int row = row0 + wm * 64 + i * 16 + quad * 4 + r;
            unsigned short* op = ys + (size_t)row * D_ + n0 + wn * 64 + r16;
#pragma unroll
            for (int j = 0; j < 4; ++j)
                op[j * 16] = f2bf(acc[i][j][r]);
        }
    }
}

// ---------------- Combine: out[t] = sum_k w_k * (sum_s y_s[row_k] + b2[e_k]) ----------------
__global__ __launch_bounds__(256) void combine_kernel(
    const unsigned short* __restrict__ y, const int* __restrict__ start,
    const int2* __restrict__ inv_ei, const float2* __restrict__ inv_w,
    const float* __restrict__ b2, float* __restrict__ out)
{
    int t = blockIdx.x;
    int tid = threadIdx.x;       // 256 threads x 4 floats = D_
    int2 ei = inv_ei[t];
    float2 w = inv_w[t];
    int e1 = ei.x & 7, x1 = ei.x >> 3;
    int e2 = ei.y & 7, x2 = ei.y >> 3;
    size_t r1 = (size_t)start[e1] + x1;
    size_t r2 = (size_t)start[e2] + x2;
    const size_t SL = (size_t)CAP * D_;
    ushort4 a0 = ((const ushort4*)(y + r1 * D_))[tid];
    ushort4 a1 = ((const ushort4*)(y + SL + r1 * D_))[tid];
    ushort4 c0 = ((const ushort4*)(y + r2 * D_))[tid];
    ushort4 c1 = ((const ushort4*)(y + SL + r2 * D_))[tid];
    float4 bA = ((const float4*)(b2 + (size_t)e1 * D_))[tid];
    float4 bB = ((const float4*)(b2 + (size_t)e2 * D_))[tid];
    float4 o;
    o.x = w.x * (bf2f(a0.x) + bf2f(a1.x) + bA.x) + w.y * (bf2f(c0.x) + bf2f(c1.x) + bB.x);
    o.y = w.x * (bf2f(a0.y) + bf2f(a1.y) + bA.y) + w.y * (bf2f(c0.y) + bf2f(c1.y) + bB.y);
    o.z = w.x * (bf2f(a0.z) + bf2f(a1.z) + bA.z) + w.y * (bf2f(c0.z) + bf2f(c1.z) + bB.z);
    o.w = w.x * (bf2f(a0.w) + bf2f(a1.w) + bA.w) + w.y * (bf2f(c0.w) + bf2f(c1.w) + bB.w);
    ((float4*)(out + (size_t)t * D_))[tid] = o;
}

// ---------------- Launch ----------------
extern "C" void kernel_launch(void* const* d_in, const int* in_sizes, int n_in,
                              void* d_out, int out_size, void* d_ws, size_t ws_size,
                              hipStream_t stream)
{
    const float* x  = (const float*)d_in[0];
    const float* Wr = (const float*)d_in[1];
    const float* W1 = (const float*)d_in[2];
    const float* b1 = (const float*)d_in[3];
    const float* W2 = (const float*)d_in[4];
    const float* b2 = (const float*)d_in[5];
    float* out = (float*)d_out;

    // ws layout (~251 MB): no more w1t/w2t — weights consumed in-place as f32
    char* ws = (char*)d_ws;
    int*    cnt      = (int*)ws;                    // 32 B
    int*    start    = (int*)(ws + 64);             // 36 B
    int*    tok_list = (int*)(ws + 256);            // 256 KiB
    int2*   inv_ei   = (int2*)(ws + 393216);        // 64 KiB
    float2* inv_w    = (float2*)(ws + 458752);      // 64 KiB
    char* p0 = ws + (1u << 20);
    unsigned short* xg = (unsigned short*)p0;                                   // 35.65 MB
    unsigned short* h  = (unsigned short*)(p0 + 35651584ull);                   // 142.6 MB
    unsigned short* y  = (unsigned short*)(p0 + 35651584ull + 142606336ull);    // 71.3 MB
    (void)ws_size; (void)in_sizes; (void)n_in; (void)out_size;

    hipMemsetAsync(ws, 0, 64, stream);   // zero cnt

    router_kernel<<<T_ / 4, 256, 0, stream>>>(x, Wr, cnt, tok_list, inv_ei, inv_w);
    offsets_kernel<<<1, 64, 0, stream>>>(cnt, start);
    gather_kernel<<<CAP, 256, 0, stream>>>(x, cnt, start, tok_list, xg);
    fc1_kernel<<<dim3(H_ / TNN, NBY), 512, 0, stream>>>(xg, W1, b1, start, h);
    fc2_kernel<<<dim3((D_ / TNN) * CK, NBY), 512, 0, stream>>>(h, W2, start, y);
    combine_kernel<<<T_, 256, 0, stream>>>(y, start, inv_ei, inv_w, b2, out);
}

// Round 2
// 989.275 us; speedup vs baseline: 1.0499x; 1.0499x over previous
//
#include <hip/hip_runtime.h>
#include <hip/hip_bf16.h>

// Problem constants (from reference)
#define E_   8
#define D_   1024
#define H_   4096
#define T_   8192      // B*S tokens
#define TMM  128       // GEMM M tile (tokens)
#define TNN  256       // GEMM N tile
#define BK   64        // GEMM K chunk (bf16)
#define CAP  17408     // 136*128 >= 16384 + 8*127 padded capacity
#define NBY  136       // CAP/TMM
#define CK   2         // fc2 K-split (K=4096 -> 2 x 2048), separate y slices

typedef __attribute__((ext_vector_type(8))) short short8;   // 8 bf16 (MFMA A/B frag, 4 VGPR)
typedef __attribute__((ext_vector_type(4))) float floatx4;  // 16x16 MFMA C/D frag

__device__ __forceinline__ unsigned short f2bf(float f) {
    unsigned u = __float_as_uint(f);
    u += 0x7fffu + ((u >> 16) & 1u);   // RNE truncate to bf16
    return (unsigned short)(u >> 16);
}
__device__ __forceinline__ float bf2f(unsigned short u) {
    return __uint_as_float((unsigned)u << 16);
}
// packed RNE f32x2 -> bf16x2 (compiler emits v_cvt_pk_bf16_f32)
__device__ __forceinline__ ushort2 cvt2(float a, float b) {
    __hip_bfloat162 t = __float22bfloat162_rn(make_float2(a, b));
    return *reinterpret_cast<ushort2*>(&t);
}

// direct global->LDS async copy, 16B/lane; lds base must be wave-uniform
#define GLP16(g, l)                                                             \
    __builtin_amdgcn_global_load_lds((const __attribute__((address_space(1))) void*)(g), \
                                     (__attribute__((address_space(3))) void*)(l), 16, 0, 0)

// ---------------- Router: 4 waves/block, 1 token/wave, float4 loads ----------------
__global__ __launch_bounds__(256) void router_kernel(
    const float* __restrict__ x, const float* __restrict__ Wr,
    int* __restrict__ cnt, int* __restrict__ tok_list,
    int2* __restrict__ inv_ei, float2* __restrict__ inv_w)
{
    int t = blockIdx.x * 4 + (threadIdx.x >> 6);
    int lane = threadIdx.x & 63;
    const float4* xr = (const float4*)(x + (size_t)t * D_);
    float acc[E_];
#pragma unroll
    for (int e = 0; e < E_; ++e) acc[e] = 0.f;
#pragma unroll
    for (int it = 0; it < D_ / 256; ++it) {
        float4 xv = xr[lane + it * 64];
#pragma unroll
        for (int e = 0; e < E_; ++e) {
            float4 wv = ((const float4*)(Wr + e * D_))[lane + it * 64];
            acc[e] += xv.x * wv.x + xv.y * wv.y + xv.z * wv.z + xv.w * wv.w;
        }
    }
#pragma unroll
    for (int e = 0; e < E_; ++e) {
#pragma unroll
        for (int off = 32; off; off >>= 1) acc[e] += __shfl_xor(acc[e], off);
    }
    if (lane == 0) {
        float m = acc[0];
#pragma unroll
        for (int e = 1; e < E_; ++e) m = fmaxf(m, acc[e]);
        float p[E_]; float s = 0.f;
#pragma unroll
        for (int e = 0; e < E_; ++e) { p[e] = expf(acc[e] - m); s += p[e]; }
        float inv = 1.f / s;
        int i1 = 0; float v1 = p[0];
#pragma unroll
        for (int e = 1; e < E_; ++e) if (p[e] > v1) { v1 = p[e]; i1 = e; }
        int i2 = -1; float v2 = -1.f;
#pragma unroll
        for (int e = 0; e < E_; ++e) { if (e == i1) continue; if (p[e] > v2) { v2 = p[e]; i2 = e; } }
        v1 *= inv; v2 *= inv;
        int pos1 = atomicAdd(&cnt[i1], 1);
        tok_list[i1 * T_ + pos1] = t;
        int pos2 = atomicAdd(&cnt[i2], 1);
        tok_list[i2 * T_ + pos2] = t;
        inv_ei[t] = make_int2(i1 | (pos1 << 3), i2 | (pos2 << 3));
        inv_w[t] = make_float2(v1, v2);
    }
}

// ---------------- Prefix: 128-aligned expert regions ----------------
__global__ void offsets_kernel(const int* __restrict__ cnt, int* __restrict__ start)
{
    if (threadIdx.x == 0) {
        int s = 0;
        for (int e = 0; e < E_; ++e) {
            start[e] = s;
            s += (cnt[e] + TMM - 1) / TMM * TMM;
        }
        start[E_] = s;
    }
}

// ---------------- Gather x rows -> bf16 ----------------
__global__ __launch_bounds__(256) void gather_kernel(
    const float* __restrict__ x, const int* __restrict__ cnt, const int* __restrict__ start,
    const int* __restrict__ tok_list, unsigned short* __restrict__ xg)
{
    int row = blockIdx.x;
    int tid = threadIdx.x;
    int tot = start[E_];
    if (row >= tot) return;
    int e = 0;
    while (e < E_ - 1 && row >= start[e + 1]) ++e;
    int idx = row - start[e];
    unsigned short* dst = xg + (size_t)row * D_;
    if (idx < cnt[e]) {
        int t = tok_list[e * T_ + idx];
        const float4* src = (const float4*)(x + (size_t)t * D_);
        float4 v = src[tid];
        ushort4 o; o.x = f2bf(v.x); o.y = f2bf(v.y); o.z = f2bf(v.z); o.w = f2bf(v.w);
        ((ushort4*)dst)[tid] = o;
    } else {
        ((ushort4*)dst)[tid] = make_ushort4(0, 0, 0, 0);  // zero pad rows
    }
}

// ---------------- fc1: h = gelu(Xg @ W1 + b1), bf16 out ----------------
// 128x256 tile, 512 threads (8 waves, 2m x 4n), each wave 4x4 frags of 16x16x32.
// A: global_load_lds from gathered bf16 xg (unchanged, verified path).
// B: fused transpose+cvt staging from the ORIGINAL f32 W1 [D][H].
//    Bsm swizzle function f(row) = ((row>>2) ^ row) & 7 (NOT row&7): the LDS
//    arbitrates in 16-lane phases, so bank-spreading bits must come from lane
//    bits 0-3.  Writer rows n = 4*lane+J give f = (lane ^ 4*lane ^ J)&7 -> all
//    8 slots per 8-lane group, + half-bit from lane b3 -> all 32 banks/phase.
//    Reader slot XOR = ((r16>>2)^r16^4*(j&1))&7 -> each slot 2x per 16 lanes
//    (b128 minimum).  Pure slot relabeling vs R1 (same coverage bijection).
__global__ __launch_bounds__(512, 4) void fc1_kernel(
    const unsigned short* __restrict__ xg, const float* __restrict__ W1,
    const float* __restrict__ b1, const int* __restrict__ start, unsigned short* __restrict__ h)
{
    __shared__ __align__(16) unsigned short Asm[TMM * BK];   // 16 KB
    __shared__ __align__(16) unsigned short Bsm[TNN * BK];   // 32 KB

    int row0 = blockIdx.y * TMM;
    int tot = start[E_];
    if (row0 >= tot) return;
    int e = 0;
    while (e < E_ - 1 && row0 >= start[e + 1]) ++e;

    int n0 = blockIdx.x * TNN;
    const unsigned short* Ag = xg + (size_t)row0 * D_;
    const float* Bg = W1 + (size_t)e * D_ * H_ + n0;   // f32 [K=D_][N=H_] panel

    int tid = threadIdx.x;
    int wid = tid >> 6, lane = tid & 63;
    int wm = wid & 1, wn = wid >> 1;          // wave covers rows wm*64+, cols wn*64+
    int quad = lane >> 4, r16 = lane & 15;
    int srow = lane >> 3;                      // 0..7
    int scol = ((lane & 7) ^ srow) * 8;        // swizzled 16B group (A path)
    int rsw = r16 & 7;                         // A reader XOR key (unchanged)
    int rbase = ((r16 >> 2) ^ r16) & 7;        // B reader XOR key (16-lane-phase safe)
    int gsl = (wid + (lane >> 4)) & 7;         // B: k-chunk this lane stages
    int kparl = (lane >> 3) & 1;               // B: k4-parity selector
    int wbase = (lane ^ (lane << 2)) & 7;      // B writer XOR key

    floatx4 acc[4][4];
#pragma unroll
    for (int i = 0; i < 4; ++i)
#pragma unroll
        for (int j = 0; j < 4; ++j) acc[i][j] = (floatx4){0.f, 0.f, 0.f, 0.f};

    for (int kc = 0; kc < D_ / BK; ++kc) {
        int k0 = kc * BK;
#pragma unroll
        for (int q = 0; q < 2; ++q) {
            int rb = wid * 16 + q * 8;
            GLP16(Ag + (size_t)(rb + srow) * D_ + k0 + scol, Asm + rb * BK);
        }
        // B staging: 2 micro-tiles of 4k x 4n per thread
#pragma unroll
        for (int m = 0; m < 2; ++m) {
            int k4 = gsl * 2 + (kparl ^ m);           // 0..15, per-lane
            const float* src = Bg + (size_t)(k0 + k4 * 4) * H_ + 4 * lane;
            float4 r0 = *(const float4*)(src);
            float4 r1 = *(const float4*)(src + H_);
            float4 r2 = *(const float4*)(src + 2 * H_);
            float4 r3 = *(const float4*)(src + 3 * H_);
            int h2 = (k4 & 1) * 4;                     // half-slot elem offset
#define BW_(J, c) { int nrow = 4 * lane + J;                                          \
        ushort2 lo = cvt2(r0.c, r1.c), hi = cvt2(r2.c, r3.c);                         \
        ushort4 o = make_ushort4(lo.x, lo.y, hi.x, hi.y);                             \
        *(ushort4*)(Bsm + nrow * BK + ((gsl ^ wbase ^ J) << 3) + h2) = o; }
            BW_(0, x) BW_(1, y) BW_(2, z) BW_(3, w)
#undef BW_
        }
        __syncthreads();
#pragma unroll
        for (int ks = 0; ks < 2; ++ks) {
            short8 af[4], bfr[4];
#pragma unroll
            for (int i = 0; i < 4; ++i)
                af[i] = *(const short8*)(Asm + (wm * 64 + i * 16 + r16) * BK + ((ks * 4 + quad) ^ rsw) * 8);
#pragma unroll
            for (int j = 0; j < 4; ++j)
                bfr[j] = *(const short8*)(Bsm + (wn * 64 + j * 16 + r16) * BK + (((ks * 4 + quad) ^ rbase ^ ((j & 1) << 2)) << 3));
#pragma unroll
            for (int i = 0; i < 4; ++i)
#pragma unroll
                for (int j = 0; j < 4; ++j)
                    acc[i][j] = __builtin_amdgcn_mfma_f32_16x16x32_bf16(af[i], bfr[j], acc[i][j], 0, 0, 0);
        }
        __syncthreads();
    }

    const float* b1e = b1 + (size_t)e * H_;
    float bj[4];
#pragma unroll
    for (int j = 0; j < 4; ++j) bj[j] = b1e[n0 + wn * 64 + j * 16 + r16];
#pragma unroll
    for (int i = 0; i < 4; ++i) {
#pragma unroll
        for (int r = 0; r < 4; ++r) {
            size_t rowg = (size_t)row0 + wm * 64 + i * 16 + quad * 4 + r;
            unsigned short* hp = h + rowg * H_ + n0 + wn * 64 + r16;
#pragma unroll
            for (int j = 0; j < 4; ++j) {
                float v = acc[i][j][r] + bj[j];
                // tanh-form gelu: v * sigmoid(1.5957691*(v + 0.044715 v^3)); max err ~3e-4
                float u = 1.5957691f * v * fmaf(0.044715f, v * v, 1.f);
                float gl = v * __builtin_amdgcn_rcpf(1.f + __expf(-u));
                hp[j * 16] = f2bf(gl);
            }
        }
    }
}

// ---------------- fc2: y_s = h @ W2 (K-slice s), bf16 out, NO atomics ----------------
// Same fused B-staging (same swizzle), from f32 W2 [K=H_][N=D_]. A: global_load_lds from h.
__global__ __launch_bounds__(512, 4) void fc2_kernel(
    const unsigned short* __restrict__ h, const float* __restrict__ W2,
    const int* __restrict__ start, unsigned short* __restrict__ y)
{
    __shared__ __align__(16) unsigned short Asm[TMM * BK];
    __shared__ __align__(16) unsigned short Bsm[TNN * BK];

    int row0 = blockIdx.y * TMM;
    int tot = start[E_];
    if (row0 >= tot) return;
    int e = 0;
    while (e < E_ - 1 && row0 >= start[e + 1]) ++e;

    int nblk = blockIdx.x & 3, ck = blockIdx.x >> 2;
    int n0 = nblk * TNN;
    const unsigned short* Ag = h + (size_t)row0 * H_;
    const float* Bg = W2 + (size_t)e * H_ * D_ + n0;   // f32 [K=H_][N=D_] panel

    int tid = threadIdx.x;
    int wid = tid >> 6, lane = tid & 63;
    int wm = wid & 1, wn = wid >> 1;
    int quad = lane >> 4, r16 = lane & 15;
    int srow = lane >> 3;
    int scol = ((lane & 7) ^ srow) * 8;
    int rsw = r16 & 7;
    int rbase = ((r16 >> 2) ^ r16) & 7;
    int gsl = (wid + (lane >> 4)) & 7;
    int kparl = (lane >> 3) & 1;
    int wbase = (lane ^ (lane << 2)) & 7;

    floatx4 acc[4][4];
#pragma unroll
    for (int i = 0; i < 4; ++i)
#pragma unroll
        for (int j = 0; j < 4; ++j) acc[i][j] = (floatx4){0.f, 0.f, 0.f, 0.f};

    const int KITERS = H_ / BK / CK;           // 32
    int kbase = ck * KITERS;
    for (int kc = kbase; kc < kbase + KITERS; ++kc) {
        int k0 = kc * BK;
#pragma unroll
        for (int q = 0; q < 2; ++q) {
            int rb = wid * 16 + q * 8;
            GLP16(Ag + (size_t)(rb + srow) * H_ + k0 + scol, Asm + rb * BK);
        }
#pragma unroll
        for (int m = 0; m < 2; ++m) {
            int k4 = gsl * 2 + (kparl ^ m);
            const float* src = Bg + (size_t)(k0 + k4 * 4) * D_ + 4 * lane;
            float4 r0 = *(const float4*)(src);
            float4 r1 = *(const float4*)(src + D_);
            float4 r2 = *(const float4*)(src + 2 * D_);
            float4 r3 = *(const float4*)(src + 3 * D_);
            int h2 = (k4 & 1) * 4;
#define BW_(J, c) { int nrow = 4 * lane + J;                                          \
        ushort2 lo = cvt2(r0.c, r1.c), hi = cvt2(r2.c, r3.c);                         \
        ushort4 o = make_ushort4(lo.x, lo.y, hi.x, hi.y);                             \
        *(ushort4*)(Bsm + nrow * BK + ((gsl ^ wbase ^ J) << 3) + h2) = o; }
            BW_(0, x) BW_(1, y) BW_(2, z) BW_(3, w)
#undef BW_
        }
        __syncthreads();
#pragma unroll
        for (int ks = 0; ks < 2; ++ks) {
            short8 af[4], bfr[4];
#pragma unroll
            for (int i = 0; i < 4; ++i)
                af[i] = *(const short8*)(Asm + (wm * 64 + i * 16 + r16) * BK + ((ks * 4 + quad) ^ rsw) * 8);
#pragma unroll
            for (int j = 0; j < 4; ++j)
                bfr[j] = *(const short8*)(Bsm + (wn * 64 + j * 16 + r16) * BK + (((ks * 4 + quad) ^ rbase ^ ((j & 1) << 2)) << 3));
#pragma unroll
            for (int i = 0; i < 4; ++i)
#pragma unroll
                for (int j = 0; j < 4; ++j)
                    acc[i][j] = __builtin_amdgcn_mfma_f32_16x16x32_bf16(af[i], bfr[j], acc[i][j], 0, 0, 0);
        }
        __syncthreads();
    }

    unsigned short* ys = y + (size_t)ck * CAP * D_;
#pragma unroll
    for (int i = 0; i < 4; ++i) {
#pragma unroll
        for (int r = 0; r < 4; ++r) {
            int row = row0 + wm * 64 + i * 16 + quad * 4 + r;
            unsigned short* op = ys + (size_t)row * D_ + n0 + wn * 64 + r16;
#pragma unroll
            for (int j = 0; j < 4; ++j)
                op[j * 16] = f2bf(acc[i][j][r]);
        }
    }
}

// ---------------- Combine: out[t] = sum_k w_k * (sum_s y_s[row_k] + b2[e_k]) ----------------
__global__ __launch_bounds__(256) void combine_kernel(
    const unsigned short* __restrict__ y, const int* __restrict__ start,
    const int2* __restrict__ inv_ei, const float2* __restrict__ inv_w,
    const float* __restrict__ b2, float* __restrict__ out)
{
    int t = blockIdx.x;
    int tid = threadIdx.x;       // 256 threads x 4 floats = D_
    int2 ei = inv_ei[t];
    float2 w = inv_w[t];
    int e1 = ei.x & 7, x1 = ei.x >> 3;
    int e2 = ei.y & 7, x2 = ei.y >> 3;
    size_t r1 = (size_t)start[e1] + x1;
    size_t r2 = (size_t)start[e2] + x2;
    const size_t SL = (size_t)CAP * D_;
    ushort4 a0 = ((const ushort4*)(y + r1 * D_))[tid];
    ushort4 a1 = ((const ushort4*)(y + SL + r1 * D_))[tid];
    ushort4 c0 = ((const ushort4*)(y + r2 * D_))[tid];
    ushort4 c1 = ((const ushort4*)(y + SL + r2 * D_))[tid];
    float4 bA = ((const float4*)(b2 + (size_t)e1 * D_))[tid];
    float4 bB = ((const float4*)(b2 + (size_t)e2 * D_))[tid];
    float4 o;
    o.x = w.x * (bf2f(a0.x) + bf2f(a1.x) + bA.x) + w.y * (bf2f(c0.x) + bf2f(c1.x) + bB.x);
    o.y = w.x * (bf2f(a0.y) + bf2f(a1.y) + bA.y) + w.y * (bf2f(c0.y) + bf2f(c1.y) + bB.y);
    o.z = w.x * (bf2f(a0.z) + bf2f(a1.z) + bA.z) + w.y * (bf2f(c0.z) + bf2f(c1.z) + bB.z);
    o.w = w.x * (bf2f(a0.w) + bf2f(a1.w) + bA.w) + w.y * (bf2f(c0.w) + bf2f(c1.w) + bB.w);
    ((float4*)(out + (size_t)t * D_))[tid] = o;
}

// ---------------- Launch ----------------
extern "C" void kernel_launch(void* const* d_in, const int* in_sizes, int n_in,
                              void* d_out, int out_size, void* d_ws, size_t ws_size,
                              hipStream_t stream)
{
    const float* x  = (const float*)d_in[0];
    const float* Wr = (const float*)d_in[1];
    const float* W1 = (const float*)d_in[2];
    const float* b1 = (const float*)d_in[3];
    const float* W2 = (const float*)d_in[4];
    const float* b2 = (const float*)d_in[5];
    float* out = (float*)d_out;

    // ws layout (~251 MB): weights consumed in-place as f32 (no transpose pass)
    char* ws = (char*)d_ws;
    int*    cnt      = (int*)ws;                    // 32 B
    int*    start    = (int*)(ws + 64);             // 36 B
    int*    tok_list = (int*)(ws + 256);            // 256 KiB
    int2*   inv_ei   = (int2*)(ws + 393216);        // 64 KiB
    float2* inv_w    = (float2*)(ws + 458752);      // 64 KiB
    char* p0 = ws + (1u << 20);
    unsigned short* xg = (unsigned short*)p0;                                   // 35.65 MB
    unsigned short* h  = (unsigned short*)(p0 + 35651584ull);                   // 142.6 MB
    unsigned short* y  = (unsigned short*)(p0 + 35651584ull + 142606336ull);    // 71.3 MB
    (void)ws_size; (void)in_sizes; (void)n_in; (void)out_size;

    hipMemsetAsync(ws, 0, 64, stream);   // zero cnt

    router_kernel<<<T_ / 4, 256, 0, stream>>>(x, Wr, cnt, tok_list, inv_ei, inv_w);
    offsets_kernel<<<1, 64, 0, stream>>>(cnt, start);
    gather_kernel<<<CAP, 256, 0, stream>>>(x, cnt, start, tok_list, xg);
    fc1_kernel<<<dim3(H_ / TNN, NBY), 512, 0, stream>>>(xg, W1, b1, start, h);
    fc2_kernel<<<dim3((D_ / TNN) * CK, NBY), 512, 0, stream>>>(h, W2, start, y);
    combine_kernel<<<T_, 256, 0, stream>>>(y, start, inv_ei, inv_w, b2, out);
}